// Round 8
// baseline (197.368 us; speedup 1.0000x reference)
//
#include <hip/hip_runtime.h>
#include <math.h>

#define HID 512
#define PPB 16              // points per block (= MFMA n-dim)
#define SLAB 512            // halfs per (state,kb) slab: 16 p x 32 k, 1 KB

typedef __attribute__((ext_vector_type(8))) _Float16 half8;   // 4 VGPRs, MFMA frag
typedef __attribute__((ext_vector_type(4))) _Float16 half4;
typedef __attribute__((ext_vector_type(4))) float f32x4;

static __device__ __forceinline__ float fast_tanh(float x) {
    float e = __expf(2.f * x);
    return 1.f - 2.f / (e + 1.f);
}

// ---------------------------------------------------------------------------
// Slab element order (lane-linear): element (p, k=kb*32+quad*8+e) of slab kb
// sits at halfs-offset  lane*8 + e  where lane = quad*16 + p.
// A wave b128 access at loff = lane*8 is a contiguous, lane-ordered 1 KB
// -> conflict-free in LDS, fully coalesced in global.
// ---------------------------------------------------------------------------

// ---------------------------------------------------------------------------
// W prep: LDS-tiled transpose + fp16 cast into lane-linear slab layout
//   Wh[(jb*16 + kb)*512 + (quad*16+l15)*8 + k8], j = jb*16+l15, k = kb*32+quad*8+k8
// Grid: 128 blocks (2 matrices x 8 jtiles x 8 ktiles of 64x64).
// Block 0 also zeroes the grid-reduction ticket counter.
// ---------------------------------------------------------------------------
__global__ __launch_bounds__(256) void prep_wt(
    const float* __restrict__ W1, const float* __restrict__ W2,
    _Float16* __restrict__ W1h, _Float16* __restrict__ W2h,
    int* __restrict__ counter)
{
    __shared__ float T[64][65];
    int b = blockIdx.x;
    if (b == 0 && threadIdx.x == 0) *counter = 0;
    const float* W = (b < 64) ? W1 : W2;
    _Float16* Wh   = (b < 64) ? W1h : W2h;
    int tb = b & 63;
    int jbG = tb >> 3, kbG = tb & 7;
    int j0 = jbG * 64, k0 = kbG * 64;
    int t = threadIdx.x;
    #pragma unroll
    for (int r = 0; r < 16; ++r) {
        int kl = r * 4 + (t >> 6);
        int jl = t & 63;
        T[kl][jl] = W[(size_t)(k0 + kl) * HID + j0 + jl];   // coalesced
    }
    __syncthreads();
    // thread -> output half8: lane-linear order within each 1KB slab
    int ljb = t >> 6;                  // local 16-j group (0..3)
    int l15 = (t >> 2) & 15;           // j within group
    int quad = t & 3;                  // k octet
    #pragma unroll
    for (int lkb = 0; lkb < 2; ++lkb) {
        half8 v;
        #pragma unroll
        for (int k8 = 0; k8 < 8; ++k8)
            v[k8] = (_Float16)T[lkb * 32 + quad * 8 + k8][ljb * 16 + l15];
        size_t out = (size_t)((jbG * 4 + ljb) * 16 + (kbG * 2 + lkb)) * SLAB
                   + (quad * 16 + l15) * 8;
        *(half8*)(Wh + out) = v;
    }
}

// ---------------------------------------------------------------------------
// One hidden-layer pass. A (B-op) in LDS slabs; W (A-op) streamed from L2
// with ping-pong register prefetch. Wave wv owns j in [64*wv, 64*wv+64)
// (4 slabs of 16 j); p-frag = l15; 4 states. acc = 64 AGPR, W regs = 32.
// FULL: emit h,t1,t2,S planes; else only h,S.
// ---------------------------------------------------------------------------
template<bool FULL>
static __device__ __forceinline__ void layer_pass(
    const _Float16* __restrict__ Wh, const float* __restrict__ bias,
    _Float16* Als, int wv, int lane)
{
    const int l15 = lane & 15, quad = lane >> 4;
    const int j0w = wv * 64;
    const int jb0 = wv * 4;                 // first 16-j slab index
    const int loff = lane * 8;              // lane-linear frag offset (halfs)

    f32x4 acc[4][4];                        // [state][jt]
    #pragma unroll
    for (int s = 0; s < 4; ++s)
        #pragma unroll
        for (int jt = 0; jt < 4; ++jt) acc[s][jt] = (f32x4)0.f;

    half8 wA[4], wB[4];
    #pragma unroll
    for (int jt = 0; jt < 4; ++jt)
        wA[jt] = *(const half8*)(Wh + (size_t)((jb0 + jt) * 16) * SLAB + loff);

    auto iter = [&](int kb, half8 (&wc)[4], half8 (&wn)[4]) {
        half8 a[4];
        #pragma unroll
        for (int s = 0; s < 4; ++s)
            a[s] = *(const half8*)(Als + (s * 16 + kb) * SLAB + loff);
        if (kb < 15) {
            #pragma unroll
            for (int jt = 0; jt < 4; ++jt)
                wn[jt] = *(const half8*)(Wh + (size_t)((jb0 + jt) * 16 + kb + 1) * SLAB + loff);
        }
        #pragma unroll
        for (int s = 0; s < 4; ++s)
            #pragma unroll
            for (int jt = 0; jt < 4; ++jt)
                acc[s][jt] = __builtin_amdgcn_mfma_f32_16x16x32_f16(
                    wc[jt], a[s], acc[s][jt], 0, 0, 0);
    };

    #pragma unroll
    for (int kb = 0; kb < 16; kb += 2) {
        iter(kb,     wA, wB);
        iter(kb + 1, wB, wA);
    }

    __syncthreads();   // all waves done reading Als; safe to overwrite

    // epilogue: D row m = jt*16+quad*4+r (j-offset), col n = p = l15.
    // Store into next-layer slab: j -> k, slab okb = j>>5, octet qo = (j&31)>>3,
    // elem e = j&7; offset = (qo*16 + l15)*8 + e.
    #pragma unroll
    for (int jt = 0; jt < 4; ++jt) {
        const int jbase = j0w + jt * 16 + quad * 4;
        f32x4 bv = *(const f32x4*)&bias[jbase];
        half4 vh, vt1, vt2, vS;
        #pragma unroll
        for (int r = 0; r < 4; ++r) {
            float a  = fast_tanh(acc[0][jt][r] + bv[r]);
            float g  = 1.f - a * a;
            float z1 = acc[1][jt][r];
            float z2 = acc[2][jt][r];
            vh[r] = (_Float16)a;
            if (FULL) {
                vt1[r] = (_Float16)(g * z1);
                vt2[r] = (_Float16)(g * z2);
            }
            vS[r] = (_Float16)(g * acc[3][jt][r] - 2.f * a * g * (z1 * z1 + z2 * z2));
        }
        const int okb = jbase >> 5;
        const int qo  = (jbase & 31) >> 3;
        const int ooff = (qo * 16 + l15) * 8 + (jbase & 7);   // jbase%8 in {0,4}
        *(half4*)(Als + (0 * 16 + okb) * SLAB + ooff) = vh;
        if (FULL) {
            *(half4*)(Als + (1 * 16 + okb) * SLAB + ooff) = vt1;
            *(half4*)(Als + (2 * 16 + okb) * SLAB + ooff) = vt2;
        }
        *(half4*)(Als + (3 * 16 + okb) * SLAB + ooff) = vS;
    }
    __syncthreads();   // Als(next layer) complete
}

// ---------------------------------------------------------------------------
// Fused: layer0 init -> L1 -> L2 -> final dot + loss partials + grid reduce.
// 16 pts/block, 512 threads (8 waves), 2 blocks/CU -> 4 waves/SIMD.
// ---------------------------------------------------------------------------
__global__ __launch_bounds__(512, 4) void pois_fused(
    const float* __restrict__ x_int, const float* __restrict__ x_bnd,
    const float* __restrict__ W0, const float* __restrict__ b0,
    const _Float16* __restrict__ W1h, const float* __restrict__ b1,
    const _Float16* __restrict__ W2h, const float* __restrict__ b2,
    const float* __restrict__ W3, const float* __restrict__ b3,
    float* __restrict__ partials, int* __restrict__ counter,
    float* __restrict__ out, int NI, int NT, int nblk)
{
    __shared__ _Float16 Als[4 * 16 * SLAB];   // 64 KB: [s][kb] lane-linear slabs
    __shared__ float scU[8][16], scL[8][16], sc[32];
    __shared__ int isLast;

    const int tid = threadIdx.x;
    const int wv = tid >> 6, lane = tid & 63;
    const int p0 = blockIdx.x * PPB;

    // ---- layer 0: wave wv fills slabs kb in {2wv, 2wv+1}; lane-linear ----
    {
        const int p = lane & 15, quad = lane >> 4;
        int gp = p0 + p;
        int gpc = (gp >= NT) ? 0 : gp;
        float xx, yy;
        if (gpc < NI) { xx = x_int[2 * gpc];        yy = x_int[2 * gpc + 1]; }
        else          { xx = x_bnd[2 * (gpc - NI)]; yy = x_bnd[2 * (gpc - NI) + 1]; }
        #pragma unroll
        for (int i = 0; i < 2; ++i) {
            const int kb = wv * 2 + i;
            const int k = kb * 32 + quad * 8;
            f32x4 w0a = *(const f32x4*)&W0[k],       w0b = *(const f32x4*)&W0[k + 4];
            f32x4 w1a = *(const f32x4*)&W0[HID + k], w1b = *(const f32x4*)&W0[HID + k + 4];
            f32x4 b0a = *(const f32x4*)&b0[k],       b0b = *(const f32x4*)&b0[k + 4];
            half8 vh, vt1, vt2, vS;
            #pragma unroll
            for (int e = 0; e < 8; ++e) {
                float w0i = (e < 4) ? w0a[e] : w0b[e - 4];
                float w1i = (e < 4) ? w1a[e] : w1b[e - 4];
                float bbi = (e < 4) ? b0a[e] : b0b[e - 4];
                float a = fast_tanh(xx * w0i + yy * w1i + bbi);
                float g = 1.f - a * a;
                vh[e]  = (_Float16)a;
                vt1[e] = (_Float16)(g * w0i);
                vt2[e] = (_Float16)(g * w1i);
                vS[e]  = (_Float16)(-2.f * a * g * (w0i * w0i + w1i * w1i));
            }
            const int off = lane * 8;               // lane-linear
            *(half8*)(Als + (0 * 16 + kb) * SLAB + off) = vh;
            *(half8*)(Als + (1 * 16 + kb) * SLAB + off) = vt1;
            *(half8*)(Als + (2 * 16 + kb) * SLAB + off) = vt2;
            *(half8*)(Als + (3 * 16 + kb) * SLAB + off) = vS;
        }
    }
    __syncthreads();

    layer_pass<true >(W1h, b1, Als, wv, lane);
    layer_pass<false>(W2h, b2, Als, wv, lane);

    // ---- final: u = h.W3 + b3 ; lap = S.W3 (lane-linear slab reads) ----
    {
        const int p = lane & 15, quad = lane >> 4;
        float u = 0.f, lap = 0.f;
        #pragma unroll
        for (int i = 0; i < 2; ++i) {
            const int kb = wv * 2 + i;
            const int k = kb * 32 + quad * 8;
            half8 hh = *(const half8*)(Als + (0 * 16 + kb) * SLAB + lane * 8);
            half8 ss = *(const half8*)(Als + (3 * 16 + kb) * SLAB + lane * 8);
            f32x4 wa = *(const f32x4*)&W3[k], wb = *(const f32x4*)&W3[k + 4];
            #pragma unroll
            for (int e = 0; e < 4; ++e) {
                u   += (float)hh[e] * wa[e] + (float)hh[e + 4] * wb[e];
                lap += (float)ss[e] * wa[e] + (float)ss[e + 4] * wb[e];
            }
        }
        // reduce over quad (lanes with same l15): xor 16, 32
        u   += __shfl_xor(u, 16);   u   += __shfl_xor(u, 32);
        lap += __shfl_xor(lap, 16); lap += __shfl_xor(lap, 32);
        if (lane < 16) { scU[wv][lane] = u; scL[wv][lane] = lap; }
    }
    __syncthreads();
    if (tid < 16) {
        const int p = tid;
        float u = 0.f, lap = 0.f;
        #pragma unroll
        for (int w = 0; w < 8; ++w) { u += scU[w][p]; lap += scL[w][p]; }
        int gp = p0 + p;
        float vi = 0.f, vb = 0.f;
        if (gp < NI) {
            const float PIf = 3.14159265358979323846f;
            float xx = x_int[2 * gp], yy = x_int[2 * gp + 1];
            float sx = sinf(PIf * xx);
            float y2 = yy * yy;
            float sy = sinf(PIf * y2), cy = cosf(PIf * y2);
            float f = -PIf * PIf * (1.f + 4.f * y2) * sx * sy + 2.f * PIf * sx * cy;
            float r = lap - f;
            vi = r * r;
        } else if (gp < NT) {
            float uu = u + b3[0];
            vb = uu * uu;
        }
        sc[p * 2] = vi; sc[p * 2 + 1] = vb;
    }
    __syncthreads();
    if (tid == 0) {
        float svi = 0.f, svb = 0.f;
        #pragma unroll
        for (int p = 0; p < PPB; ++p) { svi += sc[p * 2]; svb += sc[p * 2 + 1]; }
        partials[blockIdx.x] = svi;
        partials[nblk + blockIdx.x] = svb;
        __threadfence();
        int t = atomicAdd(counter, 1);
        isLast = (t == nblk - 1);
    }
    __syncthreads();

    // ---- last block: grid reduction ----
    if (isLast) {
        __threadfence();
        float si = 0.f, sb = 0.f;
        for (int i = tid; i < nblk; i += 512) {
            si += partials[i];
            sb += partials[nblk + i];
        }
        #pragma unroll
        for (int off = 32; off > 0; off >>= 1) {
            si += __shfl_xor(si, off);
            sb += __shfl_xor(sb, off);
        }
        __shared__ float ri[8], rb[8];
        if (lane == 0) { ri[wv] = si; rb[wv] = sb; }
        __syncthreads();
        if (tid == 0) {
            float ti = 0.f, tb = 0.f;
            #pragma unroll
            for (int w = 0; w < 8; ++w) { ti += ri[w]; tb += rb[w]; }
            float inter = ti / (float)NI;
            float bound = tb / (float)(NT - NI);
            out[0] = 0.01f * inter + bound;   // ALPHA = 0.01
            out[1] = inter;
            out[2] = bound;
        }
    }
}

// ---------------------------------------------------------------------------
extern "C" void kernel_launch(void* const* d_in, const int* in_sizes, int n_in,
                              void* d_out, int out_size, void* d_ws, size_t ws_size,
                              hipStream_t stream)
{
    const float* x_int = (const float*)d_in[0];
    const float* x_bnd = (const float*)d_in[1];
    const float* W0 = (const float*)d_in[2];
    const float* b0 = (const float*)d_in[3];
    const float* W1 = (const float*)d_in[4];
    const float* b1 = (const float*)d_in[5];
    const float* W2 = (const float*)d_in[6];
    const float* b2 = (const float*)d_in[7];
    const float* W3 = (const float*)d_in[8];
    const float* b3 = (const float*)d_in[9];

    int NI = in_sizes[0] / 2;    // 20000
    int NB = in_sizes[1] / 2;    // 800
    int NT = NI + NB;            // 20800
    int nblk = (NT + PPB - 1) / PPB;   // 1300
    (void)NB;

    // ws: [partials 2*nblk floats][counter @12.5KB][pad to 16KB][W1h 512KB][W2h 512KB]
    float* partials = (float*)d_ws;
    int* counter = (int*)((char*)d_ws + 12800);
    _Float16* W1h = (_Float16*)((char*)d_ws + 16384);
    _Float16* W2h = W1h + 262144;

    prep_wt<<<128, 256, 0, stream>>>(W1, W2, W1h, W2h, counter);

    pois_fused<<<nblk, 512, 0, stream>>>(
        x_int, x_bnd, W0, b0, W1h, b1, W2h, b2, W3, b3,
        partials, counter, (float*)d_out, NI, NT, nblk);
}

// Round 9
// 173.717 us; speedup vs baseline: 1.1361x; 1.1361x over previous
//
#include <hip/hip_runtime.h>
#include <math.h>

#define HID 512
#define PPB 32              // points per block: 2 p-frags of 16
#define SLAB 512            // halfs per slab: 16 p x 32 k, 1 KB, lane-linear

typedef __attribute__((ext_vector_type(8))) _Float16 half8;   // 4 VGPRs, MFMA frag
typedef __attribute__((ext_vector_type(4))) _Float16 half4;
typedef __attribute__((ext_vector_type(4))) float f32x4;

static __device__ __forceinline__ float fast_tanh(float x) {
    float e = __expf(2.f * x);
    return 1.f - 2.f / (e + 1.f);
}

// ---------------------------------------------------------------------------
// Slab element order (lane-linear): element (p_local, k_local=quad*8+e) sits
// at halfs-offset lane*8+e, lane = quad*16 + p_local. One wave b128 access at
// lane*8 = contiguous 1 KB: conflict-free in LDS, coalesced in global.
// A slabs: index (s*2 + ph)*16 + kb   (ph = p/16, kb = k/32). 128 KB total.
// W slabs: index jb*16 + kb           (jb = j/16). 512 KB per layer.
// ---------------------------------------------------------------------------

__global__ __launch_bounds__(256) void prep_wt(
    const float* __restrict__ W1, const float* __restrict__ W2,
    _Float16* __restrict__ W1h, _Float16* __restrict__ W2h)
{
    __shared__ float T[64][65];
    int b = blockIdx.x;
    const float* W = (b < 64) ? W1 : W2;
    _Float16* Wh   = (b < 64) ? W1h : W2h;
    int tb = b & 63;
    int jbG = tb >> 3, kbG = tb & 7;
    int j0 = jbG * 64, k0 = kbG * 64;
    int t = threadIdx.x;
    #pragma unroll
    for (int r = 0; r < 16; ++r) {
        int kl = r * 4 + (t >> 6);
        int jl = t & 63;
        T[kl][jl] = W[(size_t)(k0 + kl) * HID + j0 + jl];   // coalesced
    }
    __syncthreads();
    int ljb = t >> 6;                  // local 16-j group (0..3)
    int l15 = (t >> 2) & 15;           // j within group
    int quad = t & 3;                  // k octet
    #pragma unroll
    for (int lkb = 0; lkb < 2; ++lkb) {
        half8 v;
        #pragma unroll
        for (int k8 = 0; k8 < 8; ++k8)
            v[k8] = (_Float16)T[lkb * 32 + quad * 8 + k8][ljb * 16 + l15];
        size_t out = (size_t)((jbG * 4 + ljb) * 16 + (kbG * 2 + lkb)) * SLAB
                   + (quad * 16 + l15) * 8;
        *(half8*)(Wh + out) = v;
    }
}

// ---------------------------------------------------------------------------
// One hidden-layer pass. A (B-op) in LDS slabs; W (A-op) streamed from L2
// with ping-pong register prefetch. Wave wv (of 16) owns j in [32wv, 32wv+32)
// (2 slabs of 16 j); 2 p-frags; 4 states. acc = 64 AGPR.
// ---------------------------------------------------------------------------
template<bool FULL>
static __device__ __forceinline__ void layer_pass(
    const _Float16* __restrict__ Wh, const float* __restrict__ bias,
    _Float16* Als, int wv, int lane)
{
    const int l15 = lane & 15, quad = lane >> 4;
    const int j0w = wv * 32;
    const int jb0 = wv * 2;                 // first 16-j W slab index
    const int loff = lane * 8;              // lane-linear frag offset (halfs)

    f32x4 acc[4][2][2];                     // [state][pf][jt]
    #pragma unroll
    for (int s = 0; s < 4; ++s)
        #pragma unroll
        for (int pf = 0; pf < 2; ++pf)
            #pragma unroll
            for (int jt = 0; jt < 2; ++jt) acc[s][pf][jt] = (f32x4)0.f;

    half8 wA[2], wB[2];
    #pragma unroll
    for (int jt = 0; jt < 2; ++jt)
        wA[jt] = *(const half8*)(Wh + (size_t)((jb0 + jt) * 16) * SLAB + loff);

    auto iter = [&](int kb, half8 (&wc)[2], half8 (&wn)[2]) {
        if (kb < 15) {
            #pragma unroll
            for (int jt = 0; jt < 2; ++jt)
                wn[jt] = *(const half8*)(Wh + (size_t)((jb0 + jt) * 16 + kb + 1) * SLAB + loff);
        }
        #pragma unroll
        for (int pf = 0; pf < 2; ++pf) {
            half8 a[4];
            #pragma unroll
            for (int s = 0; s < 4; ++s)
                a[s] = *(const half8*)(Als + ((s * 2 + pf) * 16 + kb) * SLAB + loff);
            #pragma unroll
            for (int s = 0; s < 4; ++s)
                #pragma unroll
                for (int jt = 0; jt < 2; ++jt)
                    acc[s][pf][jt] = __builtin_amdgcn_mfma_f32_16x16x32_f16(
                        wc[jt], a[s], acc[s][pf][jt], 0, 0, 0);
        }
    };

    #pragma unroll
    for (int kb = 0; kb < 16; kb += 2) {
        iter(kb,     wA, wB);
        iter(kb + 1, wB, wA);
    }

    __syncthreads();   // all waves done reading Als; safe to overwrite

    // epilogue: D row m = jt*16+quad*4+r (j-offset), col p = pf*16+l15.
    // Next-layer slab for this wave's j-range is kb' = wv (j>>5 == wv).
    #pragma unroll
    for (int jt = 0; jt < 2; ++jt) {
        const int jbase = j0w + jt * 16 + quad * 4;
        const int qo = jt * 2 + (quad >> 1);        // (jbase&31)>>3
        const int e0 = (quad & 1) * 4;              // jbase&7
        f32x4 bv = *(const f32x4*)&bias[jbase];
        #pragma unroll
        for (int pf = 0; pf < 2; ++pf) {
            half4 vh, vt1, vt2, vS;
            #pragma unroll
            for (int r = 0; r < 4; ++r) {
                float a  = fast_tanh(acc[0][pf][jt][r] + bv[r]);
                float g  = 1.f - a * a;
                float z1 = acc[1][pf][jt][r];
                float z2 = acc[2][pf][jt][r];
                vh[r] = (_Float16)a;
                if (FULL) {
                    vt1[r] = (_Float16)(g * z1);
                    vt2[r] = (_Float16)(g * z2);
                }
                vS[r] = (_Float16)(g * acc[3][pf][jt][r] - 2.f * a * g * (z1 * z1 + z2 * z2));
            }
            const int ooff = (qo * 16 + l15) * 8 + e0;
            *(half4*)(Als + ((0 * 2 + pf) * 16 + wv) * SLAB + ooff) = vh;
            if (FULL) {
                *(half4*)(Als + ((1 * 2 + pf) * 16 + wv) * SLAB + ooff) = vt1;
                *(half4*)(Als + ((2 * 2 + pf) * 16 + wv) * SLAB + ooff) = vt2;
            }
            *(half4*)(Als + ((3 * 2 + pf) * 16 + wv) * SLAB + ooff) = vS;
        }
    }
    __syncthreads();   // Als(next layer) complete
}

// ---------------------------------------------------------------------------
// Fused: layer0 init -> L1 -> L2 -> final dot + loss partials.
// 32 pts/block, 1024 threads (16 waves), 1 block/CU -> 4 waves/SIMD.
// ---------------------------------------------------------------------------
__global__ __launch_bounds__(1024, 4) void pois_fused(
    const float* __restrict__ x_int, const float* __restrict__ x_bnd,
    const float* __restrict__ W0, const float* __restrict__ b0,
    const _Float16* __restrict__ W1h, const float* __restrict__ b1,
    const _Float16* __restrict__ W2h, const float* __restrict__ b2,
    const float* __restrict__ W3, const float* __restrict__ b3,
    float* __restrict__ partials, int NI, int NT, int nblk)
{
    __shared__ _Float16 Als[8 * 16 * SLAB];   // 128 KB
    __shared__ float scU[16][32], scL[16][32], sc[64];

    const int tid = threadIdx.x;
    const int wv = tid >> 6, lane = tid & 63;
    const int l15 = lane & 15, quad = lane >> 4;
    const int p0 = blockIdx.x * PPB;

    // ---- layer 0: wave wv fills slab kb = wv for both p-halves ----
    #pragma unroll
    for (int ph = 0; ph < 2; ++ph) {
        const int p = ph * 16 + l15;
        int gp = p0 + p;
        int gpc = (gp >= NT) ? 0 : gp;
        float xx, yy;
        if (gpc < NI) { xx = x_int[2 * gpc];        yy = x_int[2 * gpc + 1]; }
        else          { xx = x_bnd[2 * (gpc - NI)]; yy = x_bnd[2 * (gpc - NI) + 1]; }
        const int k = wv * 32 + quad * 8;
        f32x4 w0a = *(const f32x4*)&W0[k],       w0b = *(const f32x4*)&W0[k + 4];
        f32x4 w1a = *(const f32x4*)&W0[HID + k], w1b = *(const f32x4*)&W0[HID + k + 4];
        f32x4 b0a = *(const f32x4*)&b0[k],       b0b = *(const f32x4*)&b0[k + 4];
        half8 vh, vt1, vt2, vS;
        #pragma unroll
        for (int e = 0; e < 8; ++e) {
            float w0i = (e < 4) ? w0a[e] : w0b[e - 4];
            float w1i = (e < 4) ? w1a[e] : w1b[e - 4];
            float bbi = (e < 4) ? b0a[e] : b0b[e - 4];
            float a = fast_tanh(xx * w0i + yy * w1i + bbi);
            float g = 1.f - a * a;
            vh[e]  = (_Float16)a;
            vt1[e] = (_Float16)(g * w0i);
            vt2[e] = (_Float16)(g * w1i);
            vS[e]  = (_Float16)(-2.f * a * g * (w0i * w0i + w1i * w1i));
        }
        const int off = lane * 8;
        *(half8*)(Als + ((0 * 2 + ph) * 16 + wv) * SLAB + off) = vh;
        *(half8*)(Als + ((1 * 2 + ph) * 16 + wv) * SLAB + off) = vt1;
        *(half8*)(Als + ((2 * 2 + ph) * 16 + wv) * SLAB + off) = vt2;
        *(half8*)(Als + ((3 * 2 + ph) * 16 + wv) * SLAB + off) = vS;
    }
    __syncthreads();

    layer_pass<true >(W1h, b1, Als, wv, lane);
    layer_pass<false>(W2h, b2, Als, wv, lane);

    // ---- final: partial dots over this wave's k-slab (kb = wv) ----
    {
        const int k = wv * 32 + quad * 8;
        f32x4 wa = *(const f32x4*)&W3[k], wb = *(const f32x4*)&W3[k + 4];
        #pragma unroll
        for (int ph = 0; ph < 2; ++ph) {
            half8 hh = *(const half8*)(Als + ((0 * 2 + ph) * 16 + wv) * SLAB + lane * 8);
            half8 ss = *(const half8*)(Als + ((3 * 2 + ph) * 16 + wv) * SLAB + lane * 8);
            float u = 0.f, lap = 0.f;
            #pragma unroll
            for (int e = 0; e < 4; ++e) {
                u   += (float)hh[e] * wa[e] + (float)hh[e + 4] * wb[e];
                lap += (float)ss[e] * wa[e] + (float)ss[e + 4] * wb[e];
            }
            // reduce over quad (lanes sharing l15): xor 16, 32
            u   += __shfl_xor(u, 16);   u   += __shfl_xor(u, 32);
            lap += __shfl_xor(lap, 16); lap += __shfl_xor(lap, 32);
            if (lane < 16) { scU[wv][ph * 16 + lane] = u; scL[wv][ph * 16 + lane] = lap; }
        }
    }
    __syncthreads();
    if (tid < 32) {
        const int p = tid;
        float u = 0.f, lap = 0.f;
        #pragma unroll
        for (int w = 0; w < 16; ++w) { u += scU[w][p]; lap += scL[w][p]; }
        int gp = p0 + p;
        float vi = 0.f, vb = 0.f;
        if (gp < NI) {
            const float PIf = 3.14159265358979323846f;
            float xx = x_int[2 * gp], yy = x_int[2 * gp + 1];
            float sx = sinf(PIf * xx);
            float y2 = yy * yy;
            float sy = sinf(PIf * y2), cy = cosf(PIf * y2);
            float f = -PIf * PIf * (1.f + 4.f * y2) * sx * sy + 2.f * PIf * sx * cy;
            float r = lap - f;
            vi = r * r;
        } else if (gp < NT) {
            float uu = u + b3[0];
            vb = uu * uu;
        }
        sc[p * 2] = vi; sc[p * 2 + 1] = vb;
    }
    __syncthreads();
    if (tid == 0) {
        float svi = 0.f, svb = 0.f;
        #pragma unroll
        for (int p = 0; p < PPB; ++p) { svi += sc[p * 2]; svb += sc[p * 2 + 1]; }
        partials[blockIdx.x] = svi;
        partials[nblk + blockIdx.x] = svb;
    }
}

// ---------------------------------------------------------------------------
// Deterministic final reduction (no atomics, no fences in the hot kernel)
// ---------------------------------------------------------------------------
__global__ __launch_bounds__(256) void pois_reduce(
    const float* __restrict__ partials, float* __restrict__ out,
    int nblk, int NI, int NB)
{
    int tid = threadIdx.x;
    float si = 0.f, sb = 0.f;
    for (int i = tid; i < nblk; i += 256) {
        si += partials[i];
        sb += partials[nblk + i];
    }
    #pragma unroll
    for (int off = 32; off > 0; off >>= 1) {
        si += __shfl_xor(si, off);
        sb += __shfl_xor(sb, off);
    }
    __shared__ float ri[4], rb[4];
    int wv = tid >> 6;
    if ((tid & 63) == 0) { ri[wv] = si; rb[wv] = sb; }
    __syncthreads();
    if (tid == 0) {
        float inter = (ri[0] + ri[1] + ri[2] + ri[3]) / (float)NI;
        float bound = (rb[0] + rb[1] + rb[2] + rb[3]) / (float)NB;
        out[0] = 0.01f * inter + bound;   // ALPHA = 0.01
        out[1] = inter;
        out[2] = bound;
    }
}

// ---------------------------------------------------------------------------
extern "C" void kernel_launch(void* const* d_in, const int* in_sizes, int n_in,
                              void* d_out, int out_size, void* d_ws, size_t ws_size,
                              hipStream_t stream)
{
    const float* x_int = (const float*)d_in[0];
    const float* x_bnd = (const float*)d_in[1];
    const float* W0 = (const float*)d_in[2];
    const float* b0 = (const float*)d_in[3];
    const float* W1 = (const float*)d_in[4];
    const float* b1 = (const float*)d_in[5];
    const float* W2 = (const float*)d_in[6];
    const float* b2 = (const float*)d_in[7];
    const float* W3 = (const float*)d_in[8];
    const float* b3 = (const float*)d_in[9];

    int NI = in_sizes[0] / 2;    // 20000
    int NB = in_sizes[1] / 2;    // 800
    int NT = NI + NB;            // 20800
    int nblk = (NT + PPB - 1) / PPB;   // 650

    // ws: [partials 16KB][W1h 512KB][W2h 512KB]
    float* partials = (float*)d_ws;
    _Float16* W1h = (_Float16*)((char*)d_ws + 16384);
    _Float16* W2h = W1h + 262144;

    prep_wt<<<128, 256, 0, stream>>>(W1, W2, W1h, W2h);

    pois_fused<<<nblk, 1024, 0, stream>>>(
        x_int, x_bnd, W0, b0, W1h, b1, W2h, b2, W3, b3,
        partials, NI, NT, nblk);

    pois_reduce<<<1, 256, 0, stream>>>(partials, (float*)d_out, nblk, NI, NB);
}